// Round 19
// baseline (827.368 us; speedup 1.0000x reference)
//
#include <hip/hip_runtime.h>
#include <hip/hip_bf16.h>
#include <math.h>

typedef __hip_bfloat16 bf16;
typedef short short8 __attribute__((ext_vector_type(8)));
typedef short short4v __attribute__((ext_vector_type(4)));
typedef float f32x4 __attribute__((ext_vector_type(4)));

#define Bq 2
#define Sq 2048
#define Dq 2048
#define Hq 16
#define DHq 128
#define FFq 8192
#define Mq 4096  // Bq*Sq

__device__ __forceinline__ float b2f(bf16 x) { return __bfloat162float(x); }
__device__ __forceinline__ bf16 f2b(float x) { return __float2bfloat16(x); }

__device__ __forceinline__ void gload16(const void* g, void* lds_base) {
  __builtin_amdgcn_global_load_lds(
      (const __attribute__((address_space(1))) void*)g,
      (__attribute__((address_space(3))) void*)lds_base,
      16, 0, 0);
}

// ---------------------------------------------------------------------------
// Batched f32->bf16 conversion: one dispatch converts all 7 weight segments.
// ---------------------------------------------------------------------------
__global__ __launch_bounds__(256)
void conv_all_k(const float* __restrict__ s0, const float* __restrict__ s1,
                const float* __restrict__ s2, const float* __restrict__ s3,
                const float* __restrict__ s4, const float* __restrict__ s5,
                const float* __restrict__ s6, bf16* __restrict__ dst) {
  // layout (elements): [0,4M)=wq [4M,8M)=wk [8M,12M)=wv [12M,16M)=wo
  // [16M,32M)=w1 [32M,48M)=w3 [48M,64M)=w2
  const long total = 64L << 20;
  const long stride = (long)gridDim.x * 256 * 8;
  for (long i = ((long)blockIdx.x * 256 + threadIdx.x) * 8; i < total; i += stride) {
    const int seg4 = (int)(i >> 22);
    const float* src;
    long off;
    if (seg4 < 4)      { src = (seg4 == 0 ? s0 : seg4 == 1 ? s1 : seg4 == 2 ? s2 : s3);
                         off = i - ((long)seg4 << 22); }
    else if (seg4 < 8) { src = s4; off = i - (4L << 22); }
    else if (seg4 < 12){ src = s5; off = i - (8L << 22); }
    else               { src = s6; off = i - (12L << 22); }
    f32x4 a = *(const f32x4*)(src + off);
    f32x4 b = *(const f32x4*)(src + off + 4);
    union { short8 s; bf16 h[8]; } u;
#pragma unroll
    for (int j = 0; j < 4; ++j) { u.h[j] = f2b(a[j]); u.h[j + 4] = f2b(b[j]); }
    *(short8*)(dst + i) = u.s;
  }
}

// ---------------------------------------------------------------------------
// Scheduling macros. Phase = {RD; STG; MFMA; [vmcnt]; BAR}; single barrier.
// Round-12: fragment reads must use the 16-row pattern (2 lanes/16B block).
// Round-14: attn 2-blocks/CU co-residency does not engage; keep v3.
// Round-16/17: gemm12 XCD-chunk variants regress; plain 1D bijective is best.
// ---------------------------------------------------------------------------
#define BAR8() { asm volatile("" ::: "memory"); __builtin_amdgcn_s_barrier(); asm volatile("" ::: "memory"); }
#define VMC4() { asm volatile("s_waitcnt vmcnt(4)" ::: "memory"); __builtin_amdgcn_sched_barrier(0); }
#define VMC2() { asm volatile("s_waitcnt vmcnt(2)" ::: "memory"); __builtin_amdgcn_sched_barrier(0); }
#define VMC0() { asm volatile("s_waitcnt vmcnt(0)" ::: "memory"); __builtin_amdgcn_sched_barrier(0); }

#define STG8(Gp, ldX, rowOff, kt, XsBuf)                                        \
  gload16(Gp + (size_t)((rowOff) + w8 + lr) * (size_t)(ldX) + (kt) + sCol,      \
          &XsBuf[(rowOff) + w8][0]);                                            \
  gload16(Gp + (size_t)((rowOff) + 64 + w8 + lr) * (size_t)(ldX) + (kt) + sCol, \
          &XsBuf[(rowOff) + 64 + w8][0]);

// ---------------------------------------------------------------------------
// Shared gemm8-geometry fragment macros (16-row pattern, XOR-8 swizzle).
// ---------------------------------------------------------------------------
#define RD_A8(dst, XsBuf, mb)                                                   \
  _Pragma("unroll") for (int mi = 0; mi < 4; ++mi) {                            \
    const int ra = wmBase + ((mb) + mi) * 16 + c;                               \
    _Pragma("unroll") for (int kk = 0; kk < 2; ++kk)                            \
      dst[mi][kk] = *(const short8*)&XsBuf[ra][(((kk * 4 + g) ^ (ra & 7)) << 3)]; \
  }

#define RD_B8(dst, XsBuf, nb_)                                                  \
  _Pragma("unroll") for (int ni = 0; ni < 2; ++ni) {                            \
    const int rb = wnBase + ((nb_) + ni) * 16 + c;                              \
    _Pragma("unroll") for (int kk = 0; kk < 2; ++kk)                            \
      dst[ni][kk] = *(const short8*)&XsBuf[rb][(((kk * 4 + g) ^ (rb & 7)) << 3)]; \
  }

#define MFMA_Q8(afv, bfv, mb, nb_)                                              \
  __builtin_amdgcn_s_setprio(1);                                                \
  _Pragma("unroll") for (int mi = 0; mi < 4; ++mi)                              \
    _Pragma("unroll") for (int ni = 0; ni < 2; ++ni)                            \
      _Pragma("unroll") for (int kk = 0; kk < 2; ++kk)                          \
        acc[(mb) + mi][(nb_) + ni] = __builtin_amdgcn_mfma_f32_16x16x32_bf16(   \
            afv[mi][kk], bfv[ni][kk], acc[(mb) + mi][(nb_) + ni], 0, 0, 0);     \
  __builtin_amdgcn_s_setprio(0);

// The verified gemm8 4-phase K-loop body (2 K-tiles / iteration).
#define GEMM8_KLOOP(Ab_, Bb_, ldb_)                                             \
  for (int it = 0; it < (nt >> 1); ++it) {                                      \
    const int t = it * 2;                                                       \
    const int kt1 = (t + 1) << 6;                                               \
    const int kt2 = (t + 2 < nt ? t + 2 : nt - 1) << 6;                         \
    const int kt3 = (t + 3 < nt ? t + 3 : nt - 1) << 6;                         \
    RD_A8(af, As[0], 0); RD_B8(bf, Bs[0], 0); RD_B8(bf2, Bs[0], 2);             \
    STG8(Ab_, K, 0, kt1, As[1]); STG8(Ab_, K, 128, kt1, As[1]);                 \
    MFMA_Q8(af, bf, 0, 0); MFMA_Q8(af, bf2, 0, 2);                              \
    BAR8();                                                                     \
    RD_A8(af2, As[0], 4);                                                       \
    STG8(Bb_, ldb_, 0, kt2, Bs[0]); STG8(Bb_, ldb_, 128, kt2, Bs[0]);           \
    MFMA_Q8(af2, bf, 4, 0); MFMA_Q8(af2, bf2, 4, 2);                            \
    VMC4(); BAR8();                                                             \
    RD_A8(af, As[1], 0); RD_B8(bf, Bs[1], 0); RD_B8(bf2, Bs[1], 2);             \
    STG8(Ab_, K, 0, kt2, As[0]); STG8(Ab_, K, 128, kt2, As[0]);                 \
    MFMA_Q8(af, bf, 0, 0); MFMA_Q8(af, bf2, 0, 2);                              \
    BAR8();                                                                     \
    RD_A8(af2, As[1], 4);                                                       \
    STG8(Bb_, ldb_, 0, kt3, Bs[1]); STG8(Bb_, ldb_, 128, kt3, Bs[1]);           \
    MFMA_Q8(af2, bf, 4, 0); MFMA_Q8(af2, bf2, 4, 2);                            \
    VMC4(); BAR8();                                                             \
  }

// ---------------------------------------------------------------------------
// gemm8f: FUSED w1+w3. 256x256 tile, 8 waves, the verified 4-phase schedule
// run TWICE per block (pass 0: B=w1 -> pack u to bf16 regs; pass 1: B=w3 ->
// epilogue silu(u)*g). Removes the 134 MB ub round-trip. Inter-pass: VMC0
// drains the clamped leftover B-stage (same-thread same-address ordering);
// the pass-0 closing barrier already synced all waves. 2D XCD chunk
// (verified on w1/w3). Grid must be 32x16.
// ---------------------------------------------------------------------------
__global__ __launch_bounds__(512, 2)
void gemm8f(const bf16* __restrict__ A, const bf16* __restrict__ B1t,
            const bf16* __restrict__ B3t, bf16* __restrict__ C,
            int N, int K, int ldb) {
  __shared__ __align__(16) bf16 As[2][256][64];
  __shared__ __align__(16) bf16 Bs[2][256][64];
  const int tid = threadIdx.x;
  const int w = tid >> 6, l = tid & 63;
  const int g = l >> 4, c = l & 15;
  const int w8 = w * 8, lr = l >> 3;
  const int sCol = (((l & 7) ^ lr) << 3);

  const int orig = blockIdx.x + blockIdx.y * gridDim.x;
  const int xcd = orig & 7, idx8 = orig >> 3;
  const int bn = (xcd * 4 + (idx8 & 3)) * 256;
  const int bm = (idx8 >> 2) * 256;

  const int wmBase = (w >> 2) * 128;
  const int wnBase = (w & 3) * 64;

  const bf16* Ab = A + (size_t)bm * K;
  const int nt = K >> 6;

  short4v ureg[8][4];   // pass-0 (w1) result, bf16-packed: 64 VGPR
  f32x4 acc[8][4];
  short8 af[4][2], af2[4][2], bf[2][2], bf2[2][2];

  for (int pass = 0; pass < 2; ++pass) {
    const bf16* Bb = (pass ? B3t : B1t) + (size_t)bn * ldb;
#pragma unroll
    for (int m = 0; m < 8; ++m)
#pragma unroll
      for (int n = 0; n < 4; ++n) acc[m][n] = (f32x4){0.f, 0.f, 0.f, 0.f};

    VMC0();  // drain any leftover clamped stage from the previous pass
    STG8(Ab, K, 0, 0, As[0]); STG8(Ab, K, 128, 0, As[0]);
    STG8(Bb, ldb, 0, 0, Bs[0]); STG8(Bb, ldb, 128, 0, Bs[0]);
    STG8(Bb, ldb, 0, 64, Bs[1]); STG8(Bb, ldb, 128, 64, Bs[1]);
    VMC4(); BAR8();

    GEMM8_KLOOP(Ab, Bb, ldb);

    if (pass == 0) {
#pragma unroll
      for (int m = 0; m < 8; ++m)
#pragma unroll
        for (int n = 0; n < 4; ++n) {
          union { short4v s; bf16 h[4]; } pk;
#pragma unroll
          for (int r = 0; r < 4; ++r) pk.h[r] = f2b(acc[m][n][r]);
          ureg[m][n] = pk.s;
        }
    }
  }

  // epilogue: C = silu(u) * g   (u via bf16 roundtrip == old EPI0+EPI2 chain)
  const int rbase = bm + wmBase + g * 4;
  const int cbase = bn + wnBase + c;
#pragma unroll
  for (int m = 0; m < 8; ++m)
#pragma unroll
    for (int r = 0; r < 4; ++r) {
      const int row = rbase + m * 16 + r;
#pragma unroll
      for (int n = 0; n < 4; ++n) {
        const size_t idx = (size_t)row * N + (cbase + n * 16);
        union { short4v s; bf16 h[4]; } pk;
        pk.s = ureg[m][n];
        const float u = b2f(pk.h[r]);
        C[idx] = f2b((u / (1.f + expf(-u))) * acc[m][n][r]);
      }
    }
}

// ---------------------------------------------------------------------------
// gemm12 (rounds 11-18 verified): 128x256, BK=64, 8 waves, 4 single-barrier
// phases / 2 K-tiles, vmcnt(2). Plain 1D bijective XCD chunk.
// ---------------------------------------------------------------------------
#define RD_A12(dst, XsBuf)                                                      \
  _Pragma("unroll") for (int mi = 0; mi < 4; ++mi) {                            \
    const int ra = wmB12 + mi * 16 + c;                                         \
    _Pragma("unroll") for (int kk = 0; kk < 2; ++kk)                            \
      dst[mi][kk] = *(const short8*)&XsBuf[ra][(((kk * 4 + g) ^ (ra & 7)) << 3)]; \
  }

#define RD_B12(dst, XsBuf, nb_)                                                 \
  _Pragma("unroll") for (int ni = 0; ni < 2; ++ni) {                            \
    const int rb = wnB12 + ((nb_) + ni) * 16 + c;                               \
    _Pragma("unroll") for (int kk = 0; kk < 2; ++kk)                            \
      dst[ni][kk] = *(const short8*)&XsBuf[rb][(((kk * 4 + g) ^ (rb & 7)) << 3)]; \
  }

#define MFMA_H12(afv, bfv, nb_)                                                 \
  __builtin_amdgcn_s_setprio(1);                                                \
  _Pragma("unroll") for (int mi = 0; mi < 4; ++mi)                              \
    _Pragma("unroll") for (int ni = 0; ni < 2; ++ni)                            \
      _Pragma("unroll") for (int kk = 0; kk < 2; ++kk)                          \
        acc[mi][(nb_) + ni] = __builtin_amdgcn_mfma_f32_16x16x32_bf16(          \
            afv[mi][kk], bfv[ni][kk], acc[mi][(nb_) + ni], 0, 0, 0);            \
  __builtin_amdgcn_s_setprio(0);

template <int EPI>
__global__ __launch_bounds__(512, 2)
void gemm12(const bf16* __restrict__ A, const bf16* __restrict__ Bt,
            const void* __restrict__ R, void* __restrict__ C,
            int N, int K, int ldb, long long boff) {
  __shared__ __align__(16) bf16 As[2][128][64];
  __shared__ __align__(16) bf16 Bs[2][256][64];
  const int tid = threadIdx.x;
  const int w = tid >> 6, l = tid & 63;
  const int g = l >> 4, c = l & 15;
  const int w8 = w * 8, lr = l >> 3;
  const int sCol = (((l & 7) ^ lr) << 3);

  const int nwg = gridDim.x * gridDim.y;
  const int orig = blockIdx.x + blockIdx.y * gridDim.x;
  const int qq = nwg >> 3, rr8 = nwg & 7;
  const int xcd = orig & 7, idx8 = orig >> 3;
  const int wg = (xcd < rr8 ? xcd * (qq + 1) : rr8 * (qq + 1) + (xcd - rr8) * qq) + idx8;
  const int bm = (wg / gridDim.x) * 128;
  const int bn = (wg % gridDim.x) * 256;

  const int wmB12 = (w >> 2) * 64;
  const int wnB12 = (w & 3) * 64;

  const bf16* Ab = A + (size_t)bm * K;
  const bf16* Bb = Bt + (size_t)bn * ldb + (size_t)boff;

  f32x4 acc[4][4] = {};
  const int nt = K >> 6;

  STG8(Ab, K, 0, 0, As[0]);
  STG8(Bb, ldb, 0, 0, Bs[0]); STG8(Bb, ldb, 128, 0, Bs[0]);
  STG8(Ab, K, 0, 64, As[1]);
  VMC2(); BAR8();

  short8 af[4][2], af2[4][2], bfa[2][2], bfa2[2][2], bfb[2][2], bfb2[2][2];
  for (int it = 0; it < (nt >> 1); ++it) {
    const int t = it * 2;
    const int kt1 = (t + 1) << 6;
    const int kt2 = (t + 2 < nt ? t + 2 : nt - 1) << 6;
    const int kt3 = (t + 3 < nt ? t + 3 : nt - 1) << 6;
    RD_A12(af, As[0]); RD_B12(bfa, Bs[0], 0);
    STG8(Bb, ldb, 0, kt1, Bs[1]); STG8(Bb, ldb, 128, kt1, Bs[1]);
    MFMA_H12(af, bfa, 0);
    BAR8();
    RD_B12(bfa2, Bs[0], 2);
    STG8(Ab, K, 0, kt2, As[0]);
    MFMA_H12(af, bfa2, 2);
    VMC2(); BAR8();
    RD_A12(af2, As[1]); RD_B12(bfb, Bs[1], 0);
    STG8(Bb, ldb, 0, kt2, Bs[0]); STG8(Bb, ldb, 128, kt2, Bs[0]);
    MFMA_H12(af2, bfb, 0);
    BAR8();
    RD_B12(bfb2, Bs[1], 2);
    STG8(Ab, K, 0, kt3, As[1]);
    MFMA_H12(af2, bfb2, 2);
    VMC2(); BAR8();
  }

  const int rbase = bm + wmB12 + g * 4;
  const int cbase = bn + wnB12 + c;
#pragma unroll
  for (int m = 0; m < 4; ++m)
#pragma unroll
    for (int r = 0; r < 4; ++r) {
      const int row = rbase + m * 16 + r;
#pragma unroll
      for (int n = 0; n < 4; ++n) {
        const size_t idx = (size_t)row * N + (cbase + n * 16);
        float vacc = acc[m][n][r];
        if (EPI == 1) {
          ((float*)C)[idx] = vacc + ((const float*)R)[idx];
        } else if (EPI == 2) {
          const float u = b2f(((const bf16*)R)[idx]);
          ((bf16*)C)[idx] = f2b((u / (1.f + expf(-u))) * vacc);
        } else {
          ((bf16*)C)[idx] = f2b(vacc);
        }
      }
    }
}

// ---------------------------------------------------------------------------
// PATH B GEMM (f32 weights) - fallback only.
// ---------------------------------------------------------------------------
template <int EPI>
__global__ __launch_bounds__(256)
void gemm2(const bf16* __restrict__ A, const float* __restrict__ Bt,
           const void* __restrict__ R, void* __restrict__ C,
           int N, int K, int ldb, long long boff) {
  __shared__ __align__(16) bf16 As[128][64];
  __shared__ __align__(16) float Bsf[128][64];
  const int tid = threadIdx.x;
  const int w = tid >> 6;
  const int l = tid & 63;

  const int nwg = gridDim.x * gridDim.y;
  const int orig = blockIdx.x + blockIdx.y * gridDim.x;
  const int qq = nwg >> 3, rr8 = nwg & 7;
  const int xcd = orig & 7, idx8 = orig >> 3;
  const int wg = (xcd < rr8 ? xcd * (qq + 1) : rr8 * (qq + 1) + (xcd - rr8) * qq) + idx8;
  const int bm = (wg / gridDim.x) * 128;
  const int bn = (wg % gridDim.x) * 128;

  const int wr = (w >> 1) * 64;
  const int wc = (w & 1) * 64;
  f32x4 acc[4][4] = {};

  const bf16* Ab = A + (size_t)bm * K;
  const float* Bb = Bt + (size_t)bn * ldb + (size_t)boff;

  const int aSrcCol = (((l & 7) ^ (l >> 3)) << 3);
  const int bKey = (w * 4 + (l >> 4)) & 7;
  const int bSrcCol = (((l & 15) ^ bKey) << 2);

  for (int kt = 0; kt < K; kt += 64) {
    __syncthreads();
#pragma unroll
    for (int i = 0; i < 4; ++i)
      gload16(Ab + (size_t)(i * 32 + w * 8 + (l >> 3)) * K + kt + aSrcCol,
              &As[i * 32 + w * 8][0]);
#pragma unroll
    for (int i = 0; i < 8; ++i)
      gload16(Bb + (size_t)(i * 16 + w * 4 + (l >> 4)) * ldb + kt + bSrcCol,
              &Bsf[i * 16 + w * 4][0]);
    __syncthreads();

#pragma unroll
    for (int kk = 0; kk < 2; ++kk) {
      short8 af[4], bfv[4];
#pragma unroll
      for (int m = 0; m < 4; ++m) {
        const int ra = wr + m * 16 + (l & 15);
        const int pb = (kk * 4 + (l >> 4)) ^ (ra & 7);
        af[m] = *(const short8*)&As[ra][pb * 8];
      }
#pragma unroll
      for (int n = 0; n < 4; ++n) {
        const int rb = wc + n * 16 + (l & 15);
        const int b0 = kk * 8 + (l >> 4) * 2;
        const f32x4 x0 = *(const f32x4*)&Bsf[rb][(b0 ^ (rb & 7)) * 4];
        const f32x4 x1 = *(const f32x4*)&Bsf[rb][((b0 + 1) ^ (rb & 7)) * 4];
        union { short8 s; bf16 h[8]; } u;
#pragma unroll
        for (int j = 0; j < 4; ++j) { u.h[j] = f2b(x0[j]); u.h[j + 4] = f2b(x1[j]); }
        bfv[n] = u.s;
      }
#pragma unroll
      for (int m = 0; m < 4; ++m)
#pragma unroll
        for (int n = 0; n < 4; ++n)
          acc[m][n] = __builtin_amdgcn_mfma_f32_16x16x32_bf16(af[m], bfv[n], acc[m][n], 0, 0, 0);
    }
  }

  const int rbase = bm + wr + (l >> 4) * 4;
  const int cbase = bn + wc + (l & 15);
#pragma unroll
  for (int m = 0; m < 4; ++m)
#pragma unroll
    for (int r = 0; r < 4; ++r) {
      const int row = rbase + m * 16 + r;
#pragma unroll
      for (int n = 0; n < 4; ++n) {
        const size_t idx = (size_t)row * N + (cbase + n * 16);
        float vacc = acc[m][n][r];
        if (EPI == 1) {
          ((float*)C)[idx] = vacc + ((const float*)R)[idx];
        } else if (EPI == 2) {
          const float u = b2f(((const bf16*)R)[idx]);
          ((bf16*)C)[idx] = f2b((u / (1.f + expf(-u))) * vacc);
        } else {
          ((bf16*)C)[idx] = f2b(vacc);
        }
      }
    }
}

// ---------------------------------------------------------------------------
__global__ __launch_bounds__(256)
void rmsnorm_k(const float* __restrict__ xin, const float* __restrict__ g,
               bf16* __restrict__ out) {
  const int row = blockIdx.x;
  const int tid = threadIdx.x;
  const float* xp = xin + (size_t)row * Dq + tid * 8;
  f32x4 a = *(const f32x4*)xp, b = *(const f32x4*)(xp + 4);
  float xf[8];
#pragma unroll
  for (int j = 0; j < 4; ++j) { xf[j] = a[j]; xf[j + 4] = b[j]; }
  float ss = 0.f;
#pragma unroll
  for (int j = 0; j < 8; ++j) ss += xf[j] * xf[j];
#pragma unroll
  for (int off = 32; off > 0; off >>= 1) ss += __shfl_down(ss, off);
  __shared__ float red[4];
  if ((tid & 63) == 0) red[tid >> 6] = ss;
  __syncthreads();
  const float rms = rsqrtf((red[0] + red[1] + red[2] + red[3]) * (1.f / (float)Dq) + 1e-6f);
  const float* gp = g + tid * 8;
  f32x4 ga = *(const f32x4*)gp, gb = *(const f32x4*)(gp + 4);
  union { short8 s; bf16 h[8]; } uo;
#pragma unroll
  for (int j = 0; j < 4; ++j) {
    uo.h[j] = f2b(xf[j] * rms * ga[j]);
    uo.h[j + 4] = f2b(xf[j + 4] * rms * gb[j]);
  }
  *(short8*)(out + (size_t)row * Dq + tid * 8) = uo.s;
}

// ---------------------------------------------------------------------------
__global__ __launch_bounds__(256)
void rope_k(bf16* __restrict__ q, bf16* __restrict__ k, int ld) {
  const size_t idx = (size_t)blockIdx.x * 256 + threadIdx.x;
  const int i = (int)(idx & 63);
  const int h = (int)((idx >> 6) & 15);
  const int s = (int)((idx >> 10) & 2047);
  const int b = (int)(idx >> 21);
  // 10000^(-i/64) = exp2(-i * log2(10000)/64); exp2f is a single HW instr.
  const float f = (float)s * exp2f((float)i * -0.20762050593046439f);
  float sn, cs;
  sincosf(f, &sn, &cs);
  const size_t base = ((size_t)(b * Sq + s)) * ld + h * DHq + i;
  const float qa = b2f(q[base]), qb_ = b2f(q[base + 64]);
  q[base] = f2b(qa * cs - qb_ * sn);
  q[base + 64] = f2b(qb_ * cs + qa * sn);
  const float ka = b2f(k[base]), kb_ = b2f(k[base + 64]);
  k[base] = f2b(ka * cs - kb_ * sn);
  k[base + 64] = f2b(kb_ * cs + ka * sn);
}

// ---------------------------------------------------------------------------
// Causal flash attention v3 (rounds 7-18 verified): 256 balanced blocks
// (1/CU), 8 waves, q-tile pair (hi=(15-x)*128, lo=x*128), shared K/V staging,
// dbuf prefetch with deferred V scatter, one barrier per tile.
// ---------------------------------------------------------------------------
__device__ __forceinline__ int swz8(int row) { return (((row >> 3) ^ row) & 7) << 3; }

#define ATTN_COMPUTE(AQ, QB, QROW, M_, L_, OACC, KV0, CUR)                        \
  {                                                                               \
    f32x4 sc[4] = {};                                                             \
    __builtin_amdgcn_s_setprio(1);                                                \
    _Pragma("unroll") for (int n = 0; n < 4; ++n) {                               \
      const int krow = n * 16 + c;                                                \
      const int sw = swz8(krow);                                                  \
      _Pragma("unroll") for (int kk = 0; kk < 4; ++kk) {                          \
        short8 ak = *(const short8*)&Ks[CUR][krow][(kk * 32 + g * 8) ^ sw];       \
        sc[n] = __builtin_amdgcn_mfma_f32_16x16x32_bf16(ak, AQ[kk], sc[n], 0, 0, 0); \
      }                                                                           \
    }                                                                             \
    __builtin_amdgcn_s_setprio(0);                                                \
    float p[4][4];                                                                \
    float tmax = -3.0e38f;                                                        \
    if ((KV0) + 63 <= (QB)) {                                                     \
      _Pragma("unroll") for (int n = 0; n < 4; ++n)                               \
        _Pragma("unroll") for (int r = 0; r < 4; ++r) {                           \
          const float val = sc[n][r] * SCALE;                                     \
          p[n][r] = val;                                                          \
          tmax = fmaxf(tmax, val);                                                \
        }                                                                         \
    } else {                                                                      \
      _Pragma("unroll") for (int n = 0; n < 4; ++n)                               \
        _Pragma("unroll") for (int r = 0; r < 4; ++r) {                           \
          const int kvg = (KV0) + n * 16 + g * 4 + r;                             \
          float val = sc[n][r] * SCALE;                                           \
          if (kvg > (QROW)) val = -3.0e38f;                                       \
          p[n][r] = val;                                                          \
          tmax = fmaxf(tmax, val);                                                \
        }                                                                         \
    }                                                                             \
    tmax = fmaxf(tmax, __shfl_xor(tmax, 16));                                     \
    tmax = fmaxf(tmax, __shfl_xor(tmax, 32));                                     \
    const bool grow = !__all(tmax <= M_);                                         \
    const float m_new = grow ? fmaxf(M_, tmax) : M_;                              \
    float tsum = 0.f;                                                             \
    _Pragma("unroll") for (int n = 0; n < 4; ++n)                                 \
      _Pragma("unroll") for (int r = 0; r < 4; ++r) {                             \
        const float pv = expf(p[n][r] - m_new);                                   \
        p[n][r] = pv;                                                             \
        tsum += pv;                                                               \
      }                                                                           \
    tsum += __shfl_xor(tsum, 16);                                                 \
    tsum += __shfl_xor(tsum, 32);                                                 \
    if (grow) {                                                                   \
      const float corr = expf(M_ - m_new);                                        \
      L_ = L_ * corr + tsum;                                                      \
      M_ = m_new;                                                                 \
      _Pragma("unroll") for (int dt = 0; dt < 8; ++dt) OACC[dt] *= corr;          \
    } else {                                                                      \
      L_ += tsum;                                                                 \
    }                                                                             \
    const int keyc = (c ^ (c >> 3)) & 7;                                          \
    _Pragma("unroll") for (int n = 0; n < 4; ++n) {                               \
      union { unsigned long long u; bf16 hh[4]; } pk;                             \
      _Pragma("unroll") for (int r = 0; r < 4; ++r) pk.hh[r] = f2b(p[n][r]);      \
      const int blk = (2 * n + (g >> 1)) ^ keyc;                                  \
      *(unsigned long long*)&Ps[w][c][blk * 8 + (g & 1) * 4] = pk.u;              \
    }                                                                             \
    short8 ap[2];                                                                 \
    _Pragma("unroll") for (int kk = 0; kk < 2; ++kk)                              \
      ap[kk] = *(const short8*)&Ps[w][c][(kk * 32 + g * 8) ^ (keyc << 3)];        \
    __builtin_amdgcn_s_setprio(1);                                                \
    _Pragma("unroll") for (int dt = 0; dt < 8; ++dt) {                            \
      const int vrow = dt * 16 + c;                                               \
      const int vsw = swz8(vrow);                                                 \
      _Pragma("unroll") for (int kk = 0; kk < 2; ++kk) {                          \
        short8 av = *(const short8*)&Vt[CUR][vrow][(kk * 32 + g * 8) ^ vsw];      \
        OACC[dt] = __builtin_amdgcn_mfma_f32_16x16x32_bf16(av, ap[kk], OACC[dt], 0, 0, 0); \
      }                                                                           \
    }                                                                             \
    __builtin_amdgcn_s_setprio(0);                                                \
  }

__global__ __launch_bounds__(512)
void attn_k(const bf16* __restrict__ q, const bf16* __restrict__ k,
            const bf16* __restrict__ v, bf16* __restrict__ o, int ld) {
  __shared__ __align__(16) bf16 Ks[2][64][128];
  __shared__ __align__(16) bf16 Vt[2][128][64];
  __shared__ __align__(16) bf16 Ps[8][16][64];
  const int tid = threadIdx.x;
  const int w = tid >> 6, l = tid & 63;
  const int g = l >> 4, c = l & 15;
  const int x = blockIdx.x;
  const int h = blockIdx.y;
  const int b = blockIdx.z;
  const size_t hoff = (size_t)h * DHq;
  const float SCALE = 0.08838834764831845f;

  const int q0h = (15 - x) * 128, q0l = x * 128;
  const int qbh = q0h + w * 16, qbl = q0l + w * 16;
  const int qrh = qbh + c, qrl = qbl + c;

  short8 aqh[4], aql[4];
  {
    const bf16* qph = q + (size_t)(b * Sq + qrh) * ld + hoff + g * 8;
    const bf16* qpl = q + (size_t)(b * Sq + qrl) * ld + hoff + g * 8;
#pragma unroll
    for (int kk = 0; kk < 4; ++kk) {
      aqh[kk] = *(const short8*)(qph + kk * 32);
      aql[kk] = *(const short8*)(qpl + kk * 32);
    }
  }

  float mh = -3.0e38f, lh = 0.f, ml = -3.0e38f, ll_ = 0.f;
  f32x4 oh[8] = {}, ol[8] = {};

  const int stRow = tid >> 4;
  const int stBlk = tid & 15;
  const int ntiles = (q0h >> 6) + 2;

  {
#pragma unroll
    for (int i = 0; i < 2; ++i) {
      const int kr = i * 32 + w * 4 + (l >> 4);
      const int key = (kr ^ (kr >> 3)) & 7;
      gload16(k + (size_t)(b * Sq + kr) * ld + hoff + ((c ^ key) << 3),
              &Ks[0][i * 32 + w * 4][0]);
    }
    const int c0 = stBlk * 8;
#pragma unroll
    for (int i = 0; i < 2; ++i) {
      const int vr = i * 32 + stRow;
      union { short8 s; bf16 hh[8]; } uv;
      uv.s = *(const short8*)(v + (size_t)(b * Sq + vr) * ld + hoff + c0);
#pragma unroll
      for (int j = 0; j < 8; ++j) Vt[0][c0 + j][vr ^ swz8(c0 + j)] = uv.hh[j];
    }
  }
  __syncthreads();

  for (int t = 0; t < ntiles; ++t) {
    const int cur = t & 1, nxt = cur ^ 1;
    const int kv0 = t * 64;
    const bool pf = (t + 1 < ntiles);
    short8 vpa, vpb;
    if (pf) {
      const int kvn = kv0 + 64;
#pragma unroll
      for (int i = 0; i < 2; ++i) {
        const int kr = i * 32 + w * 4 + (l >> 4);
        const int key = (kr ^ (kr >> 3)) & 7;
        gload16(k + (size_t)(b * Sq + kvn + kr) * ld + hoff + ((c ^ key) << 3),
                &Ks[nxt][i * 32 + w * 4][0]);
      }
      vpa = *(const short8*)(v + (size_t)(b * Sq + kvn + stRow) * ld + hoff + stBlk * 8);
      vpb = *(const short8*)(v + (size_t)(b * Sq + kvn + 32 + stRow) * ld + hoff + stBlk * 8);
    }

    if (kv0 <= qbh + 15) ATTN_COMPUTE(aqh, qbh, qrh, mh, lh, oh, kv0, cur);

    if (pf) {
      const int c0 = stBlk * 8;
      union { short8 s; bf16 hh[8]; } uv;
      uv.s = vpa;
#pragma unroll
      for (int j = 0; j < 8; ++j) Vt[nxt][c0 + j][stRow ^ swz8(c0 + j)] = uv.hh[j];
      uv.s = vpb;
#pragma unroll
      for (int j = 0; j < 8; ++j) Vt[nxt][c0 + j][(32 + stRow) ^ swz8(c0 + j)] = uv.hh[j];
    }

    if (kv0 <= qbl + 15) ATTN_COMPUTE(aql, qbl, qrl, ml, ll_, ol, kv0, cur);

    __syncthreads();
  }

  {
    const float inv = 1.f / lh;
    bf16* op = o + (size_t)(b * Sq + qrh) * Dq + hoff + g * 4;
#pragma unroll
    for (int dt = 0; dt < 8; ++dt) {
      union { unsigned long long u; bf16 hh[4]; } pk;
#pragma unroll
      for (int r = 0; r < 4; ++r) pk.hh[r] = f2b(oh[dt][r] * inv);
      *(unsigned long long*)(op + dt * 16) = pk.u;
    }
  }
  {
    const float inv = 1.f / ll_;
    bf16* op = o + (size_t)(b * Sq + qrl) * Dq + hoff + g * 4;
#pragma unroll
    for (int dt = 0; dt < 8; ++dt) {
      union { unsigned long long u; bf16 hh[4]; } pk;
#pragma unroll
      for (int r = 0; r < 4; ++r) pk.hh[r] = f2b(ol[dt][r] * inv);
      *(unsigned long long*)(op + dt * 16) = pk.u;
    }
  }
}

// ---------------------------------------------------------------------------
extern "C" void kernel_launch(void* const* d_in, const int* in_sizes, int n_in,
                              void* d_out, int out_size, void* d_ws, size_t ws_size,
                              hipStream_t stream) {
  (void)in_sizes; (void)n_in; (void)out_size;
  const float* x  = (const float*)d_in[0];
  const float* wq = (const float*)d_in[2];
  const float* wk = (const float*)d_in[3];
  const float* wv = (const float*)d_in[4];
  const float* wo = (const float*)d_in[5];
  const float* w1 = (const float*)d_in[6];
  const float* w2 = (const float*)d_in[7];
  const float* w3 = (const float*)d_in[8];
  const float* ga = (const float*)d_in[9];
  const float* gf = (const float*)d_in[10];
  float* out = (float*)d_out;

  char* ws = (char*)d_ws;
  dim3 blk(256);
  dim3 gA(8, Hq, Bq);
  dim3 blkA(512);
  dim3 blk8(512);

  const size_t SZ_H   = (size_t)Mq * Dq * 2;
  const size_t SZ_QKV = (size_t)Mq * 3 * Dq * 2;
  const size_t SZ_W4  = (size_t)Dq * Dq * 2;
  const size_t SZ_W13 = (size_t)FFq * Dq * 2;
  const size_t ACT    = SZ_H + SZ_QKV;
  const size_t WTS    = 3 * SZ_W4 + SZ_W4 + 3 * SZ_W13;
  const size_t NEED   = ACT + WTS;

  if (ws_size >= NEED) {
    bf16* h    = (bf16*)(ws);
    bf16* qkv  = (bf16*)(ws + SZ_H);
    bf16* ob   = h;
    bf16* h2   = qkv;
    bf16* ub   = (bf16*)(ws + 2 * SZ_H);   // FULL M x 8192
    char* wb   = ws + ACT;
    bf16* wqkv_b = (bf16*)(wb);            // [wq|wk|wv|wo|w1|w3|w2] contiguous
    bf16* wo_b   = (bf16*)(wb + 3 * SZ_W4);
    bf16* w1_b   = (bf16*)(wb + 4 * SZ_W4);
    bf16* w3_b   = (bf16*)(wb + 4 * SZ_W4 + SZ_W13);
    bf16* w2_b   = (bf16*)(wb + 4 * SZ_W4 + 2 * SZ_W13);

    conv_all_k<<<2048, blk, 0, stream>>>(wq, wk, wv, wo, w1, w3, w2, (bf16*)wb);

    rmsnorm_k<<<Mq, blk, 0, stream>>>(x, ga, h);
    gemm12<0><<<dim3(24, 32), blk8, 0, stream>>>(h, wqkv_b, nullptr, qkv, 6144, Dq, Dq, 0);
    rope_k<<<(Bq * Sq * Hq * 64) / 256, blk, 0, stream>>>(qkv, qkv + Dq, 3 * Dq);
    attn_k<<<gA, blkA, 0, stream>>>(qkv, qkv + Dq, qkv + 2 * Dq, ob, 3 * Dq);
    gemm12<1><<<dim3(8, 32), blk8, 0, stream>>>(ob, wo_b, x, out, Dq, Dq, Dq, 0);
    rmsnorm_k<<<Mq, blk, 0, stream>>>(out, gf, h2);
    // fused FFN up+gate: ub = silu(h2*w1^T) * (h2*w3^T), no intermediate
    gemm8f<<<dim3(32, 16), blk8, 0, stream>>>(h2, w1_b, w3_b, ub, FFq, Dq, Dq);
    gemm12<1><<<dim3(8, 32), blk8, 0, stream>>>(ub, w2_b, out, out, Dq, FFq, FFq, 0);
  } else {
    // ---- PATH B: f32-weight fallback ----
    const size_t MS = (size_t)Mq * Dq * 2;
    bf16* h  = (bf16*)(ws);
    bf16* kb = (bf16*)(ws + MS);
    bf16* vb = (bf16*)(ws + 2 * MS);
    bf16* qb = (bf16*)(ws + 3 * MS);
    bf16* ub = (bf16*)(ws);
    bf16* ob = h;
    bf16* h2 = qb;

    dim3 gD(Dq / 128, Mq / 128);
    dim3 gU(32, Mq / 128);

    rmsnorm_k<<<Mq, blk, 0, stream>>>(x, ga, h);
    gemm2<0><<<gD, blk, 0, stream>>>(h, wq, nullptr, qb, Dq, Dq, Dq, 0);
    gemm2<0><<<gD, blk, 0, stream>>>(h, wk, nullptr, kb, Dq, Dq, Dq, 0);
    gemm2<0><<<gD, blk, 0, stream>>>(h, wv, nullptr, vb, Dq, Dq, Dq, 0);
    rope_k<<<(Bq * Sq * Hq * 64) / 256, blk, 0, stream>>>(qb, kb, Dq);
    attn_k<<<gA, blkA, 0, stream>>>(qb, kb, vb, ob, Dq);
    gemm2<1><<<gD, blk, 0, stream>>>(ob, wo, x, out, Dq, Dq, Dq, 0);
    rmsnorm_k<<<Mq, blk, 0, stream>>>(out, gf, h2);
    for (int hh = 0; hh < 2; ++hh) {
      const long long bo13 = (long long)hh * 4096 * 2048;
      gemm2<0><<<gU, blk, 0, stream>>>(h2, w1, nullptr, ub, 4096, Dq, Dq, bo13);
      gemm2<2><<<gU, blk, 0, stream>>>(h2, w3, ub, ub, 4096, Dq, Dq, bo13);
      gemm2<1><<<gD, blk, 0, stream>>>(ub, w2, out, out, Dq, 4096, FFq,
                                       (long long)hh * 4096);
    }
  }
}

// Round 20
// 805.313 us; speedup vs baseline: 1.0274x; 1.0274x over previous
//
#include <hip/hip_runtime.h>
#include <hip/hip_bf16.h>
#include <math.h>

typedef __hip_bfloat16 bf16;
typedef short short8 __attribute__((ext_vector_type(8)));
typedef float f32x4 __attribute__((ext_vector_type(4)));

#define Bq 2
#define Sq 2048
#define Dq 2048
#define Hq 16
#define DHq 128
#define FFq 8192
#define Mq 4096  // Bq*Sq

__device__ __forceinline__ float b2f(bf16 x) { return __bfloat162float(x); }
__device__ __forceinline__ bf16 f2b(float x) { return __float2bfloat16(x); }

__device__ __forceinline__ void gload16(const void* g, void* lds_base) {
  __builtin_amdgcn_global_load_lds(
      (const __attribute__((address_space(1))) void*)g,
      (__attribute__((address_space(3))) void*)lds_base,
      16, 0, 0);
}

// ---------------------------------------------------------------------------
// Batched f32->bf16 conversion: one dispatch converts all 7 weight segments.
// ---------------------------------------------------------------------------
__global__ __launch_bounds__(256)
void conv_all_k(const float* __restrict__ s0, const float* __restrict__ s1,
                const float* __restrict__ s2, const float* __restrict__ s3,
                const float* __restrict__ s4, const float* __restrict__ s5,
                const float* __restrict__ s6, bf16* __restrict__ dst) {
  // layout (elements): [0,4M)=wq [4M,8M)=wk [8M,12M)=wv [12M,16M)=wo
  // [16M,32M)=w1 [32M,48M)=w3 [48M,64M)=w2
  const long total = 64L << 20;
  const long stride = (long)gridDim.x * 256 * 8;
  for (long i = ((long)blockIdx.x * 256 + threadIdx.x) * 8; i < total; i += stride) {
    const int seg4 = (int)(i >> 22);
    const float* src;
    long off;
    if (seg4 < 4)      { src = (seg4 == 0 ? s0 : seg4 == 1 ? s1 : seg4 == 2 ? s2 : s3);
                         off = i - ((long)seg4 << 22); }
    else if (seg4 < 8) { src = s4; off = i - (4L << 22); }
    else if (seg4 < 12){ src = s5; off = i - (8L << 22); }
    else               { src = s6; off = i - (12L << 22); }
    f32x4 a = *(const f32x4*)(src + off);
    f32x4 b = *(const f32x4*)(src + off + 4);
    union { short8 s; bf16 h[8]; } u;
#pragma unroll
    for (int j = 0; j < 4; ++j) { u.h[j] = f2b(a[j]); u.h[j + 4] = f2b(b[j]); }
    *(short8*)(dst + i) = u.s;
  }
}

// ---------------------------------------------------------------------------
// Scheduling macros. Phase = {RD; STG; MFMA; [vmcnt]; BAR}; single barrier.
// Round-12: fragment reads must use the 16-row pattern (2 lanes/16B block).
// Round-14: attn 2-blocks/CU co-residency does not engage; keep v3.
// Round-16/17: gemm12 XCD-chunk variants regress; plain 1D bijective is best.
// Round-19: w1+w3 register fusion regresses; keep the split pair.
// ---------------------------------------------------------------------------
#define BAR8() { asm volatile("" ::: "memory"); __builtin_amdgcn_s_barrier(); asm volatile("" ::: "memory"); }
#define VMC4() { asm volatile("s_waitcnt vmcnt(4)" ::: "memory"); __builtin_amdgcn_sched_barrier(0); }
#define VMC2() { asm volatile("s_waitcnt vmcnt(2)" ::: "memory"); __builtin_amdgcn_sched_barrier(0); }

#define STG8(Gp, ldX, rowOff, kt, XsBuf)                                        \
  gload16(Gp + (size_t)((rowOff) + w8 + lr) * (size_t)(ldX) + (kt) + sCol,      \
          &XsBuf[(rowOff) + w8][0]);                                            \
  gload16(Gp + (size_t)((rowOff) + 64 + w8 + lr) * (size_t)(ldX) + (kt) + sCol, \
          &XsBuf[(rowOff) + 64 + w8][0]);

// ---------------------------------------------------------------------------
// gemm8: 256x256, BK=64, 8 waves, 16x16x32 MFMA, 4 single-barrier phases /
// 2 K-tiles, vmcnt(4). 2D XCD chunk (verified: FETCH 303->131 MB on w1/w3).
// Grid 32x16 only.
// ---------------------------------------------------------------------------
#define RD_A8(dst, XsBuf, mb)                                                   \
  _Pragma("unroll") for (int mi = 0; mi < 4; ++mi) {                            \
    const int ra = wmBase + ((mb) + mi) * 16 + c;                               \
    _Pragma("unroll") for (int kk = 0; kk < 2; ++kk)                            \
      dst[mi][kk] = *(const short8*)&XsBuf[ra][(((kk * 4 + g) ^ (ra & 7)) << 3)]; \
  }

#define RD_B8(dst, XsBuf, nb_)                                                  \
  _Pragma("unroll") for (int ni = 0; ni < 2; ++ni) {                            \
    const int rb = wnBase + ((nb_) + ni) * 16 + c;                              \
    _Pragma("unroll") for (int kk = 0; kk < 2; ++kk)                            \
      dst[ni][kk] = *(const short8*)&XsBuf[rb][(((kk * 4 + g) ^ (rb & 7)) << 3)]; \
  }

#define MFMA_Q8(afv, bfv, mb, nb_)                                              \
  __builtin_amdgcn_s_setprio(1);                                                \
  _Pragma("unroll") for (int mi = 0; mi < 4; ++mi)                              \
    _Pragma("unroll") for (int ni = 0; ni < 2; ++ni)                            \
      _Pragma("unroll") for (int kk = 0; kk < 2; ++kk)                          \
        acc[(mb) + mi][(nb_) + ni] = __builtin_amdgcn_mfma_f32_16x16x32_bf16(   \
            afv[mi][kk], bfv[ni][kk], acc[(mb) + mi][(nb_) + ni], 0, 0, 0);     \
  __builtin_amdgcn_s_setprio(0);

template <int EPI>
__global__ __launch_bounds__(512, 2)
void gemm8(const bf16* __restrict__ A, const bf16* __restrict__ Bt,
           const void* __restrict__ R, void* __restrict__ C,
           int N, int K, int ldb, long long boff) {
  __shared__ __align__(16) bf16 As[2][256][64];
  __shared__ __align__(16) bf16 Bs[2][256][64];
  const int tid = threadIdx.x;
  const int w = tid >> 6, l = tid & 63;
  const int g = l >> 4, c = l & 15;
  const int w8 = w * 8, lr = l >> 3;
  const int sCol = (((l & 7) ^ lr) << 3);

  const int orig = blockIdx.x + blockIdx.y * gridDim.x;
  const int xcd = orig & 7, idx8 = orig >> 3;
  const int bn = (xcd * 4 + (idx8 & 3)) * 256;
  const int bm = (idx8 >> 2) * 256;

  const int wmBase = (w >> 2) * 128;
  const int wnBase = (w & 3) * 64;

  const bf16* Ab = A + (size_t)bm * K;
  const bf16* Bb = Bt + (size_t)bn * ldb + (size_t)boff;

  f32x4 acc[8][4] = {};
  const int nt = K >> 6;

  STG8(Ab, K, 0, 0, As[0]); STG8(Ab, K, 128, 0, As[0]);
  STG8(Bb, ldb, 0, 0, Bs[0]); STG8(Bb, ldb, 128, 0, Bs[0]);
  STG8(Bb, ldb, 0, 64, Bs[1]); STG8(Bb, ldb, 128, 64, Bs[1]);
  VMC4(); BAR8();

  short8 af[4][2], af2[4][2], bf[2][2], bf2[2][2];
  for (int it = 0; it < (nt >> 1); ++it) {
    const int t = it * 2;
    const int kt1 = (t + 1) << 6;
    const int kt2 = (t + 2 < nt ? t + 2 : nt - 1) << 6;
    const int kt3 = (t + 3 < nt ? t + 3 : nt - 1) << 6;
    RD_A8(af, As[0], 0); RD_B8(bf, Bs[0], 0); RD_B8(bf2, Bs[0], 2);
    STG8(Ab, K, 0, kt1, As[1]); STG8(Ab, K, 128, kt1, As[1]);
    MFMA_Q8(af, bf, 0, 0); MFMA_Q8(af, bf2, 0, 2);
    BAR8();
    RD_A8(af2, As[0], 4);
    STG8(Bb, ldb, 0, kt2, Bs[0]); STG8(Bb, ldb, 128, kt2, Bs[0]);
    MFMA_Q8(af2, bf, 4, 0); MFMA_Q8(af2, bf2, 4, 2);
    VMC4(); BAR8();
    RD_A8(af, As[1], 0); RD_B8(bf, Bs[1], 0); RD_B8(bf2, Bs[1], 2);
    STG8(Ab, K, 0, kt2, As[0]); STG8(Ab, K, 128, kt2, As[0]);
    MFMA_Q8(af, bf, 0, 0); MFMA_Q8(af, bf2, 0, 2);
    BAR8();
    RD_A8(af2, As[1], 4);
    STG8(Bb, ldb, 0, kt3, Bs[1]); STG8(Bb, ldb, 128, kt3, Bs[1]);
    MFMA_Q8(af2, bf, 4, 0); MFMA_Q8(af2, bf2, 4, 2);
    VMC4(); BAR8();
  }

  const int rbase = bm + wmBase + g * 4;
  const int cbase = bn + wnBase + c;
#pragma unroll
  for (int m = 0; m < 8; ++m)
#pragma unroll
    for (int r = 0; r < 4; ++r) {
      const int row = rbase + m * 16 + r;
#pragma unroll
      for (int n = 0; n < 4; ++n) {
        const size_t idx = (size_t)row * N + (cbase + n * 16);
        float vacc = acc[m][n][r];
        if (EPI == 1) {
          ((float*)C)[idx] = vacc + ((const float*)R)[idx];
        } else if (EPI == 2) {
          const float u = b2f(((const bf16*)R)[idx]);
          ((bf16*)C)[idx] = f2b((u / (1.f + expf(-u))) * vacc);
        } else {
          ((bf16*)C)[idx] = f2b(vacc);
        }
      }
    }
}

// ---------------------------------------------------------------------------
// gemm12 (rounds 11-18 verified): 128x256, BK=64, 8 waves, 4 single-barrier
// phases / 2 K-tiles, vmcnt(2). Plain 1D bijective XCD chunk.
// ---------------------------------------------------------------------------
#define RD_A12(dst, XsBuf)                                                      \
  _Pragma("unroll") for (int mi = 0; mi < 4; ++mi) {                            \
    const int ra = wmB12 + mi * 16 + c;                                         \
    _Pragma("unroll") for (int kk = 0; kk < 2; ++kk)                            \
      dst[mi][kk] = *(const short8*)&XsBuf[ra][(((kk * 4 + g) ^ (ra & 7)) << 3)]; \
  }

#define RD_B12(dst, XsBuf, nb_)                                                 \
  _Pragma("unroll") for (int ni = 0; ni < 2; ++ni) {                            \
    const int rb = wnB12 + ((nb_) + ni) * 16 + c;                               \
    _Pragma("unroll") for (int kk = 0; kk < 2; ++kk)                            \
      dst[ni][kk] = *(const short8*)&XsBuf[rb][(((kk * 4 + g) ^ (rb & 7)) << 3)]; \
  }

#define MFMA_H12(afv, bfv, nb_)                                                 \
  __builtin_amdgcn_s_setprio(1);                                                \
  _Pragma("unroll") for (int mi = 0; mi < 4; ++mi)                              \
    _Pragma("unroll") for (int ni = 0; ni < 2; ++ni)                            \
      _Pragma("unroll") for (int kk = 0; kk < 2; ++kk)                          \
        acc[mi][(nb_) + ni] = __builtin_amdgcn_mfma_f32_16x16x32_bf16(          \
            afv[mi][kk], bfv[ni][kk], acc[mi][(nb_) + ni], 0, 0, 0);            \
  __builtin_amdgcn_s_setprio(0);

template <int EPI>
__global__ __launch_bounds__(512, 2)
void gemm12(const bf16* __restrict__ A, const bf16* __restrict__ Bt,
            const void* __restrict__ R, void* __restrict__ C,
            int N, int K, int ldb, long long boff) {
  __shared__ __align__(16) bf16 As[2][128][64];
  __shared__ __align__(16) bf16 Bs[2][256][64];
  const int tid = threadIdx.x;
  const int w = tid >> 6, l = tid & 63;
  const int g = l >> 4, c = l & 15;
  const int w8 = w * 8, lr = l >> 3;
  const int sCol = (((l & 7) ^ lr) << 3);

  const int nwg = gridDim.x * gridDim.y;
  const int orig = blockIdx.x + blockIdx.y * gridDim.x;
  const int qq = nwg >> 3, rr8 = nwg & 7;
  const int xcd = orig & 7, idx8 = orig >> 3;
  const int wg = (xcd < rr8 ? xcd * (qq + 1) : rr8 * (qq + 1) + (xcd - rr8) * qq) + idx8;
  const int bm = (wg / gridDim.x) * 128;
  const int bn = (wg % gridDim.x) * 256;

  const int wmB12 = (w >> 2) * 64;
  const int wnB12 = (w & 3) * 64;

  const bf16* Ab = A + (size_t)bm * K;
  const bf16* Bb = Bt + (size_t)bn * ldb + (size_t)boff;

  f32x4 acc[4][4] = {};
  const int nt = K >> 6;

  STG8(Ab, K, 0, 0, As[0]);
  STG8(Bb, ldb, 0, 0, Bs[0]); STG8(Bb, ldb, 128, 0, Bs[0]);
  STG8(Ab, K, 0, 64, As[1]);
  VMC2(); BAR8();

  short8 af[4][2], af2[4][2], bfa[2][2], bfa2[2][2], bfb[2][2], bfb2[2][2];
  for (int it = 0; it < (nt >> 1); ++it) {
    const int t = it * 2;
    const int kt1 = (t + 1) << 6;
    const int kt2 = (t + 2 < nt ? t + 2 : nt - 1) << 6;
    const int kt3 = (t + 3 < nt ? t + 3 : nt - 1) << 6;
    RD_A12(af, As[0]); RD_B12(bfa, Bs[0], 0);
    STG8(Bb, ldb, 0, kt1, Bs[1]); STG8(Bb, ldb, 128, kt1, Bs[1]);
    MFMA_H12(af, bfa, 0);
    BAR8();
    RD_B12(bfa2, Bs[0], 2);
    STG8(Ab, K, 0, kt2, As[0]);
    MFMA_H12(af, bfa2, 2);
    VMC2(); BAR8();
    RD_A12(af2, As[1]); RD_B12(bfb, Bs[1], 0);
    STG8(Bb, ldb, 0, kt2, Bs[0]); STG8(Bb, ldb, 128, kt2, Bs[0]);
    MFMA_H12(af2, bfb, 0);
    BAR8();
    RD_B12(bfb2, Bs[1], 2);
    STG8(Ab, K, 0, kt3, As[1]);
    MFMA_H12(af2, bfb2, 2);
    VMC2(); BAR8();
  }

  const int rbase = bm + wmB12 + g * 4;
  const int cbase = bn + wnB12 + c;
#pragma unroll
  for (int m = 0; m < 4; ++m)
#pragma unroll
    for (int r = 0; r < 4; ++r) {
      const int row = rbase + m * 16 + r;
#pragma unroll
      for (int n = 0; n < 4; ++n) {
        const size_t idx = (size_t)row * N + (cbase + n * 16);
        float vacc = acc[m][n][r];
        if (EPI == 1) {
          ((float*)C)[idx] = vacc + ((const float*)R)[idx];
        } else if (EPI == 2) {
          const float u = b2f(((const bf16*)R)[idx]);
          ((bf16*)C)[idx] = f2b((u / (1.f + expf(-u))) * vacc);
        } else {
          ((bf16*)C)[idx] = f2b(vacc);
        }
      }
    }
}

// ---------------------------------------------------------------------------
// PATH B GEMM (f32 weights) - fallback only.
// ---------------------------------------------------------------------------
template <int EPI>
__global__ __launch_bounds__(256)
void gemm2(const bf16* __restrict__ A, const float* __restrict__ Bt,
           const void* __restrict__ R, void* __restrict__ C,
           int N, int K, int ldb, long long boff) {
  __shared__ __align__(16) bf16 As[128][64];
  __shared__ __align__(16) float Bsf[128][64];
  const int tid = threadIdx.x;
  const int w = tid >> 6;
  const int l = tid & 63;

  const int nwg = gridDim.x * gridDim.y;
  const int orig = blockIdx.x + blockIdx.y * gridDim.x;
  const int qq = nwg >> 3, rr8 = nwg & 7;
  const int xcd = orig & 7, idx8 = orig >> 3;
  const int wg = (xcd < rr8 ? xcd * (qq + 1) : rr8 * (qq + 1) + (xcd - rr8) * qq) + idx8;
  const int bm = (wg / gridDim.x) * 128;
  const int bn = (wg % gridDim.x) * 128;

  const int wr = (w >> 1) * 64;
  const int wc = (w & 1) * 64;
  f32x4 acc[4][4] = {};

  const bf16* Ab = A + (size_t)bm * K;
  const float* Bb = Bt + (size_t)bn * ldb + (size_t)boff;

  const int aSrcCol = (((l & 7) ^ (l >> 3)) << 3);
  const int bKey = (w * 4 + (l >> 4)) & 7;
  const int bSrcCol = (((l & 15) ^ bKey) << 2);

  for (int kt = 0; kt < K; kt += 64) {
    __syncthreads();
#pragma unroll
    for (int i = 0; i < 4; ++i)
      gload16(Ab + (size_t)(i * 32 + w * 8 + (l >> 3)) * K + kt + aSrcCol,
              &As[i * 32 + w * 8][0]);
#pragma unroll
    for (int i = 0; i < 8; ++i)
      gload16(Bb + (size_t)(i * 16 + w * 4 + (l >> 4)) * ldb + kt + bSrcCol,
              &Bsf[i * 16 + w * 4][0]);
    __syncthreads();

#pragma unroll
    for (int kk = 0; kk < 2; ++kk) {
      short8 af[4], bfv[4];
#pragma unroll
      for (int m = 0; m < 4; ++m) {
        const int ra = wr + m * 16 + (l & 15);
        const int pb = (kk * 4 + (l >> 4)) ^ (ra & 7);
        af[m] = *(const short8*)&As[ra][pb * 8];
      }
#pragma unroll
      for (int n = 0; n < 4; ++n) {
        const int rb = wc + n * 16 + (l & 15);
        const int b0 = kk * 8 + (l >> 4) * 2;
        const f32x4 x0 = *(const f32x4*)&Bsf[rb][(b0 ^ (rb & 7)) * 4];
        const f32x4 x1 = *(const f32x4*)&Bsf[rb][((b0 + 1) ^ (rb & 7)) * 4];
        union { short8 s; bf16 h[8]; } u;
#pragma unroll
        for (int j = 0; j < 4; ++j) { u.h[j] = f2b(x0[j]); u.h[j + 4] = f2b(x1[j]); }
        bfv[n] = u.s;
      }
#pragma unroll
      for (int m = 0; m < 4; ++m)
#pragma unroll
        for (int n = 0; n < 4; ++n)
          acc[m][n] = __builtin_amdgcn_mfma_f32_16x16x32_bf16(af[m], bfv[n], acc[m][n], 0, 0, 0);
    }
  }

  const int rbase = bm + wr + (l >> 4) * 4;
  const int cbase = bn + wc + (l & 15);
#pragma unroll
  for (int m = 0; m < 4; ++m)
#pragma unroll
    for (int r = 0; r < 4; ++r) {
      const int row = rbase + m * 16 + r;
#pragma unroll
      for (int n = 0; n < 4; ++n) {
        const size_t idx = (size_t)row * N + (cbase + n * 16);
        float vacc = acc[m][n][r];
        if (EPI == 1) {
          ((float*)C)[idx] = vacc + ((const float*)R)[idx];
        } else if (EPI == 2) {
          const float u = b2f(((const bf16*)R)[idx]);
          ((bf16*)C)[idx] = f2b((u / (1.f + expf(-u))) * vacc);
        } else {
          ((bf16*)C)[idx] = f2b(vacc);
        }
      }
    }
}

// ---------------------------------------------------------------------------
__global__ __launch_bounds__(256)
void rmsnorm_k(const float* __restrict__ xin, const float* __restrict__ g,
               bf16* __restrict__ out) {
  const int row = blockIdx.x;
  const int tid = threadIdx.x;
  const float* xp = xin + (size_t)row * Dq + tid * 8;
  f32x4 a = *(const f32x4*)xp, b = *(const f32x4*)(xp + 4);
  float xf[8];
#pragma unroll
  for (int j = 0; j < 4; ++j) { xf[j] = a[j]; xf[j + 4] = b[j]; }
  float ss = 0.f;
#pragma unroll
  for (int j = 0; j < 8; ++j) ss += xf[j] * xf[j];
#pragma unroll
  for (int off = 32; off > 0; off >>= 1) ss += __shfl_down(ss, off);
  __shared__ float red[4];
  if ((tid & 63) == 0) red[tid >> 6] = ss;
  __syncthreads();
  const float rms = rsqrtf((red[0] + red[1] + red[2] + red[3]) * (1.f / (float)Dq) + 1e-6f);
  const float* gp = g + tid * 8;
  f32x4 ga = *(const f32x4*)gp, gb = *(const f32x4*)(gp + 4);
  union { short8 s; bf16 h[8]; } uo;
#pragma unroll
  for (int j = 0; j < 4; ++j) {
    uo.h[j] = f2b(xf[j] * rms * ga[j]);
    uo.h[j + 4] = f2b(xf[j + 4] * rms * gb[j]);
  }
  *(short8*)(out + (size_t)row * Dq + tid * 8) = uo.s;
}

// ---------------------------------------------------------------------------
__global__ __launch_bounds__(256)
void rope_k(bf16* __restrict__ q, bf16* __restrict__ k, int ld) {
  const size_t idx = (size_t)blockIdx.x * 256 + threadIdx.x;
  const int i = (int)(idx & 63);
  const int h = (int)((idx >> 6) & 15);
  const int s = (int)((idx >> 10) & 2047);
  const int b = (int)(idx >> 21);
  // 10000^(-i/64) = exp2(-i * log2(10000)/64); exp2f is a single HW instr.
  const float f = (float)s * exp2f((float)i * -0.20762050593046439f);
  float sn, cs;
  sincosf(f, &sn, &cs);
  const size_t base = ((size_t)(b * Sq + s)) * ld + h * DHq + i;
  const float qa = b2f(q[base]), qb_ = b2f(q[base + 64]);
  q[base] = f2b(qa * cs - qb_ * sn);
  q[base + 64] = f2b(qb_ * cs + qa * sn);
  const float ka = b2f(k[base]), kb_ = b2f(k[base + 64]);
  k[base] = f2b(ka * cs - kb_ * sn);
  k[base + 64] = f2b(kb_ * cs + ka * sn);
}

// ---------------------------------------------------------------------------
// Causal flash attention v3 (rounds 7-18 verified): 256 balanced blocks
// (1/CU), 8 waves, q-tile pair (hi=(15-x)*128, lo=x*128), shared K/V staging,
// dbuf prefetch with deferred V scatter, one barrier per tile.
// ---------------------------------------------------------------------------
__device__ __forceinline__ int swz8(int row) { return (((row >> 3) ^ row) & 7) << 3; }

#define ATTN_COMPUTE(AQ, QB, QROW, M_, L_, OACC, KV0, CUR)                        \
  {                                                                               \
    f32x4 sc[4] = {};                                                             \
    __builtin_amdgcn_s_setprio(1);                                                \
    _Pragma("unroll") for (int n = 0; n < 4; ++n) {                               \
      const int krow = n * 16 + c;                                                \
      const int sw = swz8(krow);                                                  \
      _Pragma("unroll") for (int kk = 0; kk < 4; ++kk) {                          \
        short8 ak = *(const short8*)&Ks[CUR][krow][(kk * 32 + g * 8) ^ sw];       \
        sc[n] = __builtin_amdgcn_mfma_f32_16x16x32_bf16(ak, AQ[kk], sc[n], 0, 0, 0); \
      }                                                                           \
    }                                                                             \
    __builtin_amdgcn_s_setprio(0);                                                \
    float p[4][4];                                                                \
    float tmax = -3.0e38f;                                                        \
    if ((KV0) + 63 <= (QB)) {                                                     \
      _Pragma("unroll") for (int n = 0; n < 4; ++n)                               \
        _Pragma("unroll") for (int r = 0; r < 4; ++r) {                           \
          const float val = sc[n][r] * SCALE;                                     \
          p[n][r] = val;                                                          \
          tmax = fmaxf(tmax, val);                                                \
        }                                                                         \
    } else {                                                                      \
      _Pragma("unroll") for (int n = 0; n < 4; ++n)                               \
        _Pragma("unroll") for (int r = 0; r < 4; ++r) {                           \
          const int kvg = (KV0) + n * 16 + g * 4 + r;                             \
          float val = sc[n][r] * SCALE;                                           \
          if (kvg > (QROW)) val = -3.0e38f;                                       \
          p[n][r] = val;                                                          \
          tmax = fmaxf(tmax, val);                                                \
        }                                                                         \
    }                                                                             \
    tmax = fmaxf(tmax, __shfl_xor(tmax, 16));                                     \
    tmax = fmaxf(tmax, __shfl_xor(tmax, 32));                                     \
    const bool grow = !__all(tmax <= M_);                                         \
    const float m_new = grow ? fmaxf(M_, tmax) : M_;                              \
    float tsum = 0.f;                                                             \
    _Pragma("unroll") for (int n = 0; n < 4; ++n)                                 \
      _Pragma("unroll") for (int r = 0; r < 4; ++r) {                             \
        const float pv = expf(p[n][r] - m_new);                                   \
        p[n][r] = pv;                                                             \
        tsum += pv;                                                               \
      }                                                                           \
    tsum += __shfl_xor(tsum, 16);                                                 \
    tsum += __shfl_xor(tsum, 32);                                                 \
    if (grow) {                                                                   \
      const float corr = expf(M_ - m_new);                                        \
      L_ = L_ * corr + tsum;                                                      \
      M_ = m_new;                                                                 \
      _Pragma("unroll") for (int dt = 0; dt < 8; ++dt) OACC[dt] *= corr;          \
    } else {                                                                      \
      L_ += tsum;                                                                 \
    }                                                                             \
    const int keyc = (c ^ (c >> 3)) & 7;                                          \
    _Pragma("unroll") for (int n = 0; n < 4; ++n) {                               \
      union { unsigned long long u; bf16 hh[4]; } pk;                             \
      _Pragma("unroll") for (int r = 0; r < 4; ++r) pk.hh[r] = f2b(p[n][r]);      \
      const int blk = (2 * n + (g >> 1)) ^ keyc;                                  \
      *(unsigned long long*)&Ps[w][c][blk * 8 + (g & 1) * 4] = pk.u;              \
    }                                                                             \
    short8 ap[2];                                                                 \
    _Pragma("unroll") for (int kk = 0; kk < 2; ++kk)                              \
      ap[kk] = *(const short8*)&Ps[w][c][(kk * 32 + g * 8) ^ (keyc << 3)];        \
    __builtin_amdgcn_s_setprio(1);                                                \
    _Pragma("unroll") for (int dt = 0; dt < 8; ++dt) {                            \
      const int vrow = dt * 16 + c;                                               \
      const int vsw = swz8(vrow);                                                 \
      _Pragma("unroll") for (int kk = 0; kk < 2; ++kk) {                          \
        short8 av = *(const short8*)&Vt[CUR][vrow][(kk * 32 + g * 8) ^ vsw];      \
        OACC[dt] = __builtin_amdgcn_mfma_f32_16x16x32_bf16(av, ap[kk], OACC[dt], 0, 0, 0); \
      }                                                                           \
    }                                                                             \
    __builtin_amdgcn_s_setprio(0);                                                \
  }

__global__ __launch_bounds__(512)
void attn_k(const bf16* __restrict__ q, const bf16* __restrict__ k,
            const bf16* __restrict__ v, bf16* __restrict__ o, int ld) {
  __shared__ __align__(16) bf16 Ks[2][64][128];
  __shared__ __align__(16) bf16 Vt[2][128][64];
  __shared__ __align__(16) bf16 Ps[8][16][64];
  const int tid = threadIdx.x;
  const int w = tid >> 6, l = tid & 63;
  const int g = l >> 4, c = l & 15;
  const int x = blockIdx.x;
  const int h = blockIdx.y;
  const int b = blockIdx.z;
  const size_t hoff = (size_t)h * DHq;
  const float SCALE = 0.08838834764831845f;

  const int q0h = (15 - x) * 128, q0l = x * 128;
  const int qbh = q0h + w * 16, qbl = q0l + w * 16;
  const int qrh = qbh + c, qrl = qbl + c;

  short8 aqh[4], aql[4];
  {
    const bf16* qph = q + (size_t)(b * Sq + qrh) * ld + hoff + g * 8;
    const bf16* qpl = q + (size_t)(b * Sq + qrl) * ld + hoff + g * 8;
#pragma unroll
    for (int kk = 0; kk < 4; ++kk) {
      aqh[kk] = *(const short8*)(qph + kk * 32);
      aql[kk] = *(const short8*)(qpl + kk * 32);
    }
  }

  float mh = -3.0e38f, lh = 0.f, ml = -3.0e38f, ll_ = 0.f;
  f32x4 oh[8] = {}, ol[8] = {};

  const int stRow = tid >> 4;
  const int stBlk = tid & 15;
  const int ntiles = (q0h >> 6) + 2;

  {
#pragma unroll
    for (int i = 0; i < 2; ++i) {
      const int kr = i * 32 + w * 4 + (l >> 4);
      const int key = (kr ^ (kr >> 3)) & 7;
      gload16(k + (size_t)(b * Sq + kr) * ld + hoff + ((c ^ key) << 3),
              &Ks[0][i * 32 + w * 4][0]);
    }
    const int c0 = stBlk * 8;
#pragma unroll
    for (int i = 0; i < 2; ++i) {
      const int vr = i * 32 + stRow;
      union { short8 s; bf16 hh[8]; } uv;
      uv.s = *(const short8*)(v + (size_t)(b * Sq + vr) * ld + hoff + c0);
#pragma unroll
      for (int j = 0; j < 8; ++j) Vt[0][c0 + j][vr ^ swz8(c0 + j)] = uv.hh[j];
    }
  }
  __syncthreads();

  for (int t = 0; t < ntiles; ++t) {
    const int cur = t & 1, nxt = cur ^ 1;
    const int kv0 = t * 64;
    const bool pf = (t + 1 < ntiles);
    short8 vpa, vpb;
    if (pf) {
      const int kvn = kv0 + 64;
#pragma unroll
      for (int i = 0; i < 2; ++i) {
        const int kr = i * 32 + w * 4 + (l >> 4);
        const int key = (kr ^ (kr >> 3)) & 7;
        gload16(k + (size_t)(b * Sq + kvn + kr) * ld + hoff + ((c ^ key) << 3),
                &Ks[nxt][i * 32 + w * 4][0]);
      }
      vpa = *(const short8*)(v + (size_t)(b * Sq + kvn + stRow) * ld + hoff + stBlk * 8);
      vpb = *(const short8*)(v + (size_t)(b * Sq + kvn + 32 + stRow) * ld + hoff + stBlk * 8);
    }

    if (kv0 <= qbh + 15) ATTN_COMPUTE(aqh, qbh, qrh, mh, lh, oh, kv0, cur);

    if (pf) {
      const int c0 = stBlk * 8;
      union { short8 s; bf16 hh[8]; } uv;
      uv.s = vpa;
#pragma unroll
      for (int j = 0; j < 8; ++j) Vt[nxt][c0 + j][stRow ^ swz8(c0 + j)] = uv.hh[j];
      uv.s = vpb;
#pragma unroll
      for (int j = 0; j < 8; ++j) Vt[nxt][c0 + j][(32 + stRow) ^ swz8(c0 + j)] = uv.hh[j];
    }

    if (kv0 <= qbl + 15) ATTN_COMPUTE(aql, qbl, qrl, ml, ll_, ol, kv0, cur);

    __syncthreads();
  }

  {
    const float inv = 1.f / lh;
    bf16* op = o + (size_t)(b * Sq + qrh) * Dq + hoff + g * 4;
#pragma unroll
    for (int dt = 0; dt < 8; ++dt) {
      union { unsigned long long u; bf16 hh[4]; } pk;
#pragma unroll
      for (int r = 0; r < 4; ++r) pk.hh[r] = f2b(oh[dt][r] * inv);
      *(unsigned long long*)(op + dt * 16) = pk.u;
    }
  }
  {
    const float inv = 1.f / ll_;
    bf16* op = o + (size_t)(b * Sq + qrl) * Dq + hoff + g * 4;
#pragma unroll
    for (int dt = 0; dt < 8; ++dt) {
      union { unsigned long long u; bf16 hh[4]; } pk;
#pragma unroll
      for (int r = 0; r < 4; ++r) pk.hh[r] = f2b(ol[dt][r] * inv);
      *(unsigned long long*)(op + dt * 16) = pk.u;
    }
  }
}

// ---------------------------------------------------------------------------
extern "C" void kernel_launch(void* const* d_in, const int* in_sizes, int n_in,
                              void* d_out, int out_size, void* d_ws, size_t ws_size,
                              hipStream_t stream) {
  (void)in_sizes; (void)n_in; (void)out_size;
  const float* x  = (const float*)d_in[0];
  const float* wq = (const float*)d_in[2];
  const float* wk = (const float*)d_in[3];
  const float* wv = (const float*)d_in[4];
  const float* wo = (const float*)d_in[5];
  const float* w1 = (const float*)d_in[6];
  const float* w2 = (const float*)d_in[7];
  const float* w3 = (const float*)d_in[8];
  const float* ga = (const float*)d_in[9];
  const float* gf = (const float*)d_in[10];
  float* out = (float*)d_out;

  char* ws = (char*)d_ws;
  dim3 blk(256);
  dim3 gA(8, Hq, Bq);
  dim3 blkA(512);
  dim3 blk8(512);

  const size_t SZ_H   = (size_t)Mq * Dq * 2;
  const size_t SZ_QKV = (size_t)Mq * 3 * Dq * 2;
  const size_t SZ_W4  = (size_t)Dq * Dq * 2;
  const size_t SZ_W13 = (size_t)FFq * Dq * 2;
  const size_t ACT    = SZ_H + SZ_QKV;
  const size_t WTS    = 3 * SZ_W4 + SZ_W4 + 3 * SZ_W13;
  const size_t NEED   = ACT + WTS;

  if (ws_size >= NEED) {
    bf16* h    = (bf16*)(ws);
    bf16* qkv  = (bf16*)(ws + SZ_H);
    bf16* ob   = h;
    bf16* h2   = qkv;
    bf16* ub   = (bf16*)(ws + 2 * SZ_H);   // FULL M x 8192
    char* wb   = ws + ACT;
    bf16* wqkv_b = (bf16*)(wb);            // [wq|wk|wv|wo|w1|w3|w2] contiguous
    bf16* wo_b   = (bf16*)(wb + 3 * SZ_W4);
    bf16* w1_b   = (bf16*)(wb + 4 * SZ_W4);
    bf16* w3_b   = (bf16*)(wb + 4 * SZ_W4 + SZ_W13);
    bf16* w2_b   = (bf16*)(wb + 4 * SZ_W4 + 2 * SZ_W13);

    conv_all_k<<<2048, blk, 0, stream>>>(wq, wk, wv, wo, w1, w3, w2, (bf16*)wb);

    rmsnorm_k<<<Mq, blk, 0, stream>>>(x, ga, h);
    gemm12<0><<<dim3(24, 32), blk8, 0, stream>>>(h, wqkv_b, nullptr, qkv, 6144, Dq, Dq, 0);
    rope_k<<<(Bq * Sq * Hq * 64) / 256, blk, 0, stream>>>(qkv, qkv + Dq, 3 * Dq);
    attn_k<<<gA, blkA, 0, stream>>>(qkv, qkv + Dq, qkv + 2 * Dq, ob, 3 * Dq);
    gemm12<1><<<dim3(8, 32), blk8, 0, stream>>>(ob, wo_b, x, out, Dq, Dq, Dq, 0);
    rmsnorm_k<<<Mq, blk, 0, stream>>>(out, gf, h2);
    gemm8<0><<<dim3(32, 16), blk8, 0, stream>>>(h2, w1_b, nullptr, ub, FFq, Dq, Dq, 0);
    gemm8<2><<<dim3(32, 16), blk8, 0, stream>>>(h2, w3_b, ub, ub, FFq, Dq, Dq, 0);
    gemm12<1><<<dim3(8, 32), blk8, 0, stream>>>(ub, w2_b, out, out, Dq, FFq, FFq, 0);
  } else {
    // ---- PATH B: f32-weight fallback ----
    const size_t MS = (size_t)Mq * Dq * 2;
    bf16* h  = (bf16*)(ws);
    bf16* kb = (bf16*)(ws + MS);
    bf16* vb = (bf16*)(ws + 2 * MS);
    bf16* qb = (bf16*)(ws + 3 * MS);
    bf16* ub = (bf16*)(ws);
    bf16* ob = h;
    bf16* h2 = qb;

    dim3 gD(Dq / 128, Mq / 128);
    dim3 gU(32, Mq / 128);

    rmsnorm_k<<<Mq, blk, 0, stream>>>(x, ga, h);
    gemm2<0><<<gD, blk, 0, stream>>>(h, wq, nullptr, qb, Dq, Dq, Dq, 0);
    gemm2<0><<<gD, blk, 0, stream>>>(h, wk, nullptr, kb, Dq, Dq, Dq, 0);
    gemm2<0><<<gD, blk, 0, stream>>>(h, wv, nullptr, vb, Dq, Dq, Dq, 0);
    rope_k<<<(Bq * Sq * Hq * 64) / 256, blk, 0, stream>>>(qb, kb, Dq);
    attn_k<<<gA, blkA, 0, stream>>>(qb, kb, vb, ob, Dq);
    gemm2<1><<<gD, blk, 0, stream>>>(ob, wo, x, out, Dq, Dq, Dq, 0);
    rmsnorm_k<<<Mq, blk, 0, stream>>>(out, gf, h2);
    for (int hh = 0; hh < 2; ++hh) {
      const long long bo13 = (long long)hh * 4096 * 2048;
      gemm2<0><<<gU, blk, 0, stream>>>(h2, w1, nullptr, ub, 4096, Dq, Dq, bo13);
      gemm2<2><<<gU, blk, 0, stream>>>(h2, w3, ub, ub, 4096, Dq, Dq, bo13);
      gemm2<1><<<gD, blk, 0, stream>>>(ub, w2, out, out, Dq, 4096, FFq,
                                       (long long)hh * 4096);
    }
  }
}